// Round 2
// baseline (12195.361 us; speedup 1.0000x reference)
//
#include <hip/hip_runtime.h>
#include <stdint.h>

// ---------------------------------------------------------------------------
// DiffusionModel: 100 fused steps of x <- x + B*(x@Wx + t*csum + b) + s*noise
// Rows independent across the whole chain -> single persistent kernel,
// x resident in regs (fp32 master) + LDS (bf16 image for MFMA A-frags).
// Noise: JAX threefry2x32-20, PARTITIONABLE path (default since jax 0.4.36):
//   per element e: counter=(0,e), key=fold_in(key(42),t), bits = out0 ^ out1.
// Noise VALU dominates (~160G lane-ops) -> interleaved into the K-chunk loop
// so MFMA + global_load_lds staging hide under it.
// ---------------------------------------------------------------------------

typedef __attribute__((ext_vector_type(8))) short short8;
typedef __attribute__((ext_vector_type(4))) float f32x4;

#define XS_STRIDE 520          // bf16 elems per x-row in LDS (512 + 8 pad, keeps 16B align)
#define WB_STRIDE 40           // bf16 per n-row in W chunk blob (32 + 8 pad, keeps 16B align)
#define CHUNK_BYTES (512 * WB_STRIDE * 2)   // 40960 B per K-chunk blob
#define NSTEP 100

__device__ __forceinline__ uint32_t rotl32(uint32_t x, int r) {
  return (x << r) | (x >> (32 - r));   // -> v_alignbit_b32
}

// Threefry-2x32, 20 rounds, exactly as jax._src.prng.threefry2x32
__device__ __forceinline__ void tf_rounds(uint32_t k0, uint32_t k1, uint32_t k2,
                                          uint32_t& a, uint32_t& b) {
  a += k0; b += k1;
#define TFR(r) { a += b; b = rotl32(b, (r)); b ^= a; }
  TFR(13) TFR(15) TFR(26) TFR(6)   a += k1; b += k2 + 1u;
  TFR(17) TFR(29) TFR(16) TFR(24)  a += k2; b += k0 + 2u;
  TFR(13) TFR(15) TFR(26) TFR(6)   a += k0; b += k1 + 3u;
  TFR(17) TFR(29) TFR(16) TFR(24)  a += k1; b += k2 + 4u;
  TFR(13) TFR(15) TFR(26) TFR(6)   a += k2; b += k0 + 5u;
#undef TFR
}

// bits -> uniform[-0.99999994, 1) -> sqrt(2)*erfinv(u), matching
// jax.random.normal (XLA ErfInv f32 = Giles poly, w = -log1p(-u*u)).
// log1p replaced by hw log: |err| ~2 ulp of w -> <<1e-3 in xT, irrelevant.
__device__ __forceinline__ float gauss_from_bits(uint32_t bits) {
  const float lo = __uint_as_float(0xBF7FFFFFu);   // nextafter(-1,0)
  float f = __uint_as_float((bits >> 9) | 0x3F800000u) - 1.0f;  // [0,1)
  float u = fmaxf(lo, fmaf(f, 2.0f, lo));          // (hi-lo) rounds to 2.0f exactly
  float om = fmaf(u, -u, 1.0f);                    // 1 - u^2 (single rounding, >0)
  float w = -__logf(om);
  float p;
  if (w < 5.0f) {
    w -= 2.5f;
    p =            2.81022636e-08f;
    p = fmaf(p, w, 3.43273939e-07f);
    p = fmaf(p, w, -3.5233877e-06f);
    p = fmaf(p, w, -4.39150654e-06f);
    p = fmaf(p, w, 0.00021858087f);
    p = fmaf(p, w, -0.00125372503f);
    p = fmaf(p, w, -0.00417768164f);
    p = fmaf(p, w, 0.246640727f);
    p = fmaf(p, w, 1.50140941f);
  } else {
    w = sqrtf(w) - 3.0f;
    p =            -0.000200214257f;
    p = fmaf(p, w, 0.000100950558f);
    p = fmaf(p, w, 0.00134934322f);
    p = fmaf(p, w, -0.00367342844f);
    p = fmaf(p, w, 0.00573950773f);
    p = fmaf(p, w, -0.0076224613f);
    p = fmaf(p, w, 0.00943887047f);
    p = fmaf(p, w, 1.00167406f);
    p = fmaf(p, w, 2.83297682f);
  }
  return 1.41421356f * (p * u);   // sqrt(2) * erfinv(u)
}

// f32 -> bf16 RNE (bit trick; NaN irrelevant here)
__device__ __forceinline__ uint16_t f2bf(float f) {
  uint32_t u = __float_as_uint(f);
  u += 0x7FFFu + ((u >> 16) & 1u);
  return (uint16_t)(u >> 16);
}

// async global->LDS, 16B per lane (wave-uniform base + lane*16 pattern)
__device__ __forceinline__ void load_lds_128(const void* g, void* l) {
  auto* gp = reinterpret_cast<const __attribute__((address_space(1))) uint32_t*>(
      reinterpret_cast<uintptr_t>(g));
  auto* lp = reinterpret_cast<__attribute__((address_space(3))) uint32_t*>(
      reinterpret_cast<uintptr_t>(l));
  __builtin_amdgcn_global_load_lds(gp, lp, 16, 0, 0);
}

// --------------------------------------------------------------------------
// Pre-pass 1: convert Wx (rows 0..511 of W) to bf16 blob in the exact LDS
// image the main kernel stages: chunk c (k in [32c,32c+32)), layout [n][40]
// (pad cols 32..39 never read; garbage OK).
// --------------------------------------------------------------------------
__global__ void prep_w_kernel(const float* __restrict__ W, uint16_t* __restrict__ blob) {
  int id = blockIdx.x * 256 + threadIdx.x;
  if (id >= 512 * 512) return;
  int k = id >> 9;        // feature (K) index
  int n = id & 511;       // output col
  float v = W[k * 512 + n];
  int c = k >> 5, kk = k & 31;
  blob[c * (512 * WB_STRIDE) + n * WB_STRIDE + kk] = f2bf(v);
}

// Pre-pass 2: csum[n] = sum_j W[512+j][n]  (rank-1 t-embedding part, fp32)
__global__ void prep_csum_kernel(const float* __restrict__ W, float* __restrict__ csum) {
  int n = blockIdx.x * 256 + threadIdx.x;
  if (n >= 512) return;
  float s = 0.0f;
  for (int j = 0; j < 512; ++j) s += W[(512 + j) * 512 + n];
  csum[n] = s;
}

// --------------------------------------------------------------------------
// Main fused kernel. 512 blocks x 512 threads (8 waves). Block b owns rows
// [64b, 64b+64). Wave w computes output cols [64w, 64w+64).
// MFMA 16x16x32 bf16: A[m=lane&15][k=q*8+j], B[k=q*8+j][n=lane&15] from the
// [n][k] blob, C row=4q+reg, col=lane&15 (m89/m91-verified layouts).
// Per K-chunk c: stage W chunk + read A-frags, then generate noise for 4 of
// this thread's 64 elements (mt=c&3, nt=c>>2) -- MFMA/staging hide under it.
// --------------------------------------------------------------------------
__global__ __launch_bounds__(512, 2) void diffuse_kernel(
    const float* __restrict__ x0, const uint16_t* __restrict__ wblob,
    const float* __restrict__ csum, const float* __restrict__ bvec,
    float* __restrict__ out) {
  __shared__ alignas(16) uint16_t xs[64 * XS_STRIDE];   // 66560 B  bf16 x image
  __shared__ alignas(16) uint16_t wb[512 * WB_STRIDE];  // 40960 B  W chunk

  const int tid = threadIdx.x;
  const int l15 = tid & 15;
  const int q   = (tid >> 4) & 3;
  const int wv  = tid >> 6;        // wave 0..7
  const int blk = blockIdx.x;      // 0..511

  int   ncol[4];
  float csr[4], br[4];
#pragma unroll
  for (int nt = 0; nt < 4; ++nt) {
    ncol[nt] = wv * 64 + nt * 16 + l15;
    csr[nt]  = csum[ncol[nt]];
    br[nt]   = bvec[ncol[nt]];
  }

  // fp32 master copy of x, C-fragment layout: element (mt,nt)[j] is
  // local row m = 16*mt + 4*q + j (global row 64*blk + m), col ncol[nt].
  f32x4 xr[4][4];
#pragma unroll
  for (int mt = 0; mt < 4; ++mt)
#pragma unroll
    for (int j = 0; j < 4; ++j) {
      int gr = blk * 64 + mt * 16 + q * 4 + j;
#pragma unroll
      for (int nt = 0; nt < 4; ++nt)
        xr[mt][nt][j] = x0[gr * 512 + ncol[nt]];
    }

  // initial bf16 image
#pragma unroll
  for (int mt = 0; mt < 4; ++mt)
#pragma unroll
    for (int j = 0; j < 4; ++j) {
      int m = mt * 16 + q * 4 + j;
#pragma unroll
      for (int nt = 0; nt < 4; ++nt)
        xs[m * XS_STRIDE + ncol[nt]] = f2bf(xr[mt][nt][j]);
    }

  const float sq2b = sqrtf(0.02f);   // sqrt(2*beta), f32 like reference
  const f32x4 vzero = {0.0f, 0.0f, 0.0f, 0.0f};

  for (int t = 0; t < NSTEP; ++t) {
    // key_t = fold_in(key(42), t) = threefry((0,42), (0,t))  [unchanged by
    // partitionable mode]
    uint32_t kt0 = 0u, kt1 = (uint32_t)t;
    tf_rounds(0u, 42u, 42u ^ 0x1BD11BDAu, kt0, kt1);
    const uint32_t kk2 = kt0 ^ kt1 ^ 0x1BD11BDAu;

    f32x4 acc[4][4];
#pragma unroll
    for (int mt = 0; mt < 4; ++mt)
#pragma unroll
      for (int nt = 0; nt < 4; ++nt)
        acc[mt][nt] = vzero;

#pragma unroll
    for (int c = 0; c < 16; ++c) {
      __syncthreads();              // wb reusable; (c==0) also fences xs writes
      // stage W chunk c: 512 thr x 5 x 16B = 40960 B, blob is verbatim LDS image
#pragma unroll
      for (int i = 0; i < 5; ++i) {
        int off = i * 8192 + tid * 16;
        load_lds_128((const char*)wblob + c * CHUNK_BYTES + off, (char*)wb + off);
      }
      // A-frags from xs (stable during K-loop)
      short8 af[4];
#pragma unroll
      for (int mt = 0; mt < 4; ++mt)
        af[mt] = *(const short8*)&xs[(mt * 16 + l15) * XS_STRIDE + c * 32 + q * 8];

      // ---- interleaved noise: elements (mt=c&3, nt=c>>2, j=0..3) ----
      // partitionable threefry: counter=(0,e), 32-bit bits = out0 ^ out1.
      // Noise-add commutes with the score update; GEMM reads xs, not xr.
      {
        const int mtn = c & 3, ntn = c >> 2;
        const uint32_t ebase =
            (uint32_t)((blk * 64 + mtn * 16 + q * 4) * 512 + ncol[ntn]);
#pragma unroll
        for (int j = 0; j < 4; ++j) {
          uint32_t a = 0u, b = ebase + (uint32_t)(j * 512);
          tf_rounds(kt0, kt1, kk2, a, b);
          float n = gauss_from_bits(a ^ b);
          xr[mtn][ntn][j] = fmaf(sq2b, n, xr[mtn][ntn][j]);
        }
      }
      __syncthreads();              // staging complete (vmcnt drained at barrier)
      short8 bf[4];
#pragma unroll
      for (int nt = 0; nt < 4; ++nt)
        bf[nt] = *(const short8*)&wb[ncol[nt] * WB_STRIDE + q * 8];
#pragma unroll
      for (int mt = 0; mt < 4; ++mt)
#pragma unroll
        for (int nt = 0; nt < 4; ++nt)
          acc[mt][nt] = __builtin_amdgcn_mfma_f32_16x16x32_bf16(
              af[mt], bf[nt], acc[mt][nt], 0, 0, 0);
    }
    __syncthreads();   // all xs reads done before update overwrites

    // epilogue: score update (noise already folded into xr) + new bf16 image
    const float tf = (float)t;
    float tc[4];
#pragma unroll
    for (int nt = 0; nt < 4; ++nt) tc[nt] = fmaf(tf, csr[nt], br[nt]);

#pragma unroll
    for (int mt = 0; mt < 4; ++mt) {
#pragma unroll
      for (int nt = 0; nt < 4; ++nt) {
#pragma unroll
        for (int j = 0; j < 4; ++j) {
          int m = mt * 16 + q * 4 + j;
          float sc = acc[mt][nt][j] + tc[nt];
          float xv = fmaf(0.01f, sc, xr[mt][nt][j]);
          xr[mt][nt][j] = xv;
          xs[m * XS_STRIDE + ncol[nt]] = f2bf(xv);
        }
      }
    }
  }

  // final store (fp32)
#pragma unroll
  for (int mt = 0; mt < 4; ++mt)
#pragma unroll
    for (int j = 0; j < 4; ++j) {
      int gr = blk * 64 + mt * 16 + q * 4 + j;
#pragma unroll
      for (int nt = 0; nt < 4; ++nt)
        out[gr * 512 + ncol[nt]] = xr[mt][nt][j];
    }
}

extern "C" void kernel_launch(void* const* d_in, const int* in_sizes, int n_in,
                              void* d_out, int out_size, void* d_ws, size_t ws_size,
                              hipStream_t stream) {
  const float* x0 = (const float*)d_in[0];   // (32768, 512)
  const float* W  = (const float*)d_in[1];   // (1024, 512)
  const float* bv = (const float*)d_in[2];   // (512,)
  float* out = (float*)d_out;

  uint16_t* blob = (uint16_t*)d_ws;                          // 16*40960 = 655360 B
  float* csum = (float*)((char*)d_ws + 16 * CHUNK_BYTES);    // +2048 B

  prep_w_kernel<<<dim3(1024), dim3(256), 0, stream>>>(W, blob);
  prep_csum_kernel<<<dim3(2), dim3(256), 0, stream>>>(W, csum);
  diffuse_kernel<<<dim3(512), dim3(512), 0, stream>>>(x0, blob, csum, bv, out);
}

// Round 3
// 9292.930 us; speedup vs baseline: 1.3123x; 1.3123x over previous
//
#include <hip/hip_runtime.h>
#include <stdint.h>

// ---------------------------------------------------------------------------
// DiffusionModel: 100 fused steps of x <- x + B*(x@Wx + t*csum + b) + s*noise
// Rows independent across the chain -> one persistent kernel; x fp32 master in
// registers (MFMA C-layout), bf16 image in LDS for A-frags.
// W (bf16 [chunk][n][32] blob) streams DIRECTLY global->VGPR as B-fragments:
// coalesced 16B/lane, L2-cached, prefetched 1 chunk ahead. No LDS staging, no
// barriers inside the K-loop -> step body is one barrier-free region; the
// noise VALU (~2.5 ms floor) hides MFMA + B-load latency via wave drift.
// Noise: JAX threefry2x32-20, partitionable path: counter=(0,e), bits=a^b.
// ---------------------------------------------------------------------------

typedef __attribute__((ext_vector_type(8))) short short8;
typedef __attribute__((ext_vector_type(4))) float f32x4;

#define XS_STRIDE 520          // bf16 elems per x-row in LDS (512+8 pad, 16B-aligned rows)
#define NSTEP 100

__device__ __forceinline__ uint32_t rotl32(uint32_t x, int r) {
  return (x << r) | (x >> (32 - r));   // -> v_alignbit_b32
}

// Threefry-2x32, 20 rounds, exactly as jax._src.prng.threefry2x32
__device__ __forceinline__ void tf_rounds(uint32_t k0, uint32_t k1, uint32_t k2,
                                          uint32_t& a, uint32_t& b) {
  a += k0; b += k1;
#define TFR(r) { a += b; b = rotl32(b, (r)); b ^= a; }
  TFR(13) TFR(15) TFR(26) TFR(6)   a += k1; b += k2 + 1u;
  TFR(17) TFR(29) TFR(16) TFR(24)  a += k2; b += k0 + 2u;
  TFR(13) TFR(15) TFR(26) TFR(6)   a += k0; b += k1 + 3u;
  TFR(17) TFR(29) TFR(16) TFR(24)  a += k1; b += k2 + 4u;
  TFR(13) TFR(15) TFR(26) TFR(6)   a += k2; b += k0 + 5u;
#undef TFR
}

// bits -> uniform[-0.99999994, 1) -> sqrt(2)*erfinv(u)  (XLA/Giles erfinv;
// log1p -> hw log of fma(u,-u,1): ~2ulp, irrelevant vs 1.6 threshold)
__device__ __forceinline__ float gauss_from_bits(uint32_t bits) {
  const float lo = __uint_as_float(0xBF7FFFFFu);   // nextafter(-1,0)
  float f = __uint_as_float((bits >> 9) | 0x3F800000u) - 1.0f;  // [0,1)
  float u = fmaxf(lo, fmaf(f, 2.0f, lo));
  float om = fmaf(u, -u, 1.0f);                    // 1-u^2 > 0
  float w = -__logf(om);
  float p;
  if (w < 5.0f) {                                  // ~99.7% of lanes
    float z = w - 2.5f;
    p =            2.81022636e-08f;
    p = fmaf(p, z, 3.43273939e-07f);
    p = fmaf(p, z, -3.5233877e-06f);
    p = fmaf(p, z, -4.39150654e-06f);
    p = fmaf(p, z, 0.00021858087f);
    p = fmaf(p, z, -0.00125372503f);
    p = fmaf(p, z, -0.00417768164f);
    p = fmaf(p, z, 0.246640727f);
    p = fmaf(p, z, 1.50140941f);
  } else {
    float z = sqrtf(w) - 3.0f;
    p =            -0.000200214257f;
    p = fmaf(p, z, 0.000100950558f);
    p = fmaf(p, z, 0.00134934322f);
    p = fmaf(p, z, -0.00367342844f);
    p = fmaf(p, z, 0.00573950773f);
    p = fmaf(p, z, -0.0076224613f);
    p = fmaf(p, z, 0.00943887047f);
    p = fmaf(p, z, 1.00167406f);
    p = fmaf(p, z, 2.83297682f);
  }
  return 1.41421356f * (p * u);   // sqrt(2) * erfinv(u)
}

// f32 -> bf16 RNE (bit trick)
__device__ __forceinline__ uint16_t f2bf(float f) {
  uint32_t u = __float_as_uint(f);
  u += 0x7FFFu + ((u >> 16) & 1u);
  return (uint16_t)(u >> 16);
}

// --------------------------------------------------------------------------
// Pre-pass 1: Wx (rows 0..511 of W) -> bf16 blob, UNPADDED [c][n][32]:
// chunk c holds k in [32c,32c+32); B-frag for (c,n,q) = 16B at n*64 + q*16.
// --------------------------------------------------------------------------
__global__ void prep_w_kernel(const float* __restrict__ W, uint16_t* __restrict__ blob) {
  int id = blockIdx.x * 256 + threadIdx.x;
  if (id >= 512 * 512) return;
  int k = id >> 9;        // feature (K) index
  int n = id & 511;       // output col
  float v = W[k * 512 + n];
  int c = k >> 5, kk = k & 31;
  blob[c * 16384 + n * 32 + kk] = f2bf(v);
}

// Pre-pass 2: csum[n] = sum_j W[512+j][n]  (rank-1 t-embedding part)
__global__ void prep_csum_kernel(const float* __restrict__ W, float* __restrict__ csum) {
  int n = blockIdx.x * 256 + threadIdx.x;
  if (n >= 512) return;
  float s = 0.0f;
  for (int j = 0; j < 512; ++j) s += W[(512 + j) * 512 + n];
  csum[n] = s;
}

// --------------------------------------------------------------------------
// Main fused kernel. 512 blocks x 512 threads (8 waves). Block b owns rows
// [64b, 64b+64). Wave w computes cols [64w, 64w+64).
// MFMA 16x16x32 bf16: A[m=lane&15][k=q*8+j] (from xs), B[k][n=lane&15]
// (direct global 16B load), C row=4q+reg, col=lane&15.
// Step body = ONE barrier-free region: K-loop (prefetched B) then noise +
// update into xr. Only the xs-rewrite phase is barrier-fenced (2/step).
// --------------------------------------------------------------------------
__global__ __launch_bounds__(512, 2) void diffuse_kernel(
    const float* __restrict__ x0, const uint16_t* __restrict__ wblob,
    const float* __restrict__ csum, const float* __restrict__ bvec,
    float* __restrict__ out) {
  __shared__ alignas(16) uint16_t xs[64 * XS_STRIDE];   // 66560 B (only LDS)

  const int tid = threadIdx.x;
  const int l15 = tid & 15;
  const int q   = (tid >> 4) & 3;
  const int wv  = tid >> 6;        // wave 0..7
  const int blk = blockIdx.x;      // 0..511

  int   ncol[4];
  float csr[4], br[4];
#pragma unroll
  for (int nt = 0; nt < 4; ++nt) {
    ncol[nt] = wv * 64 + nt * 16 + l15;
    csr[nt]  = csum[ncol[nt]];
    br[nt]   = bvec[ncol[nt]];
  }

  // per-thread B-frag base pointers (elems): c*16384 + ncol*32 + q*8
  const uint16_t* bbase[4];
#pragma unroll
  for (int nt = 0; nt < 4; ++nt)
    bbase[nt] = wblob + ncol[nt] * 32 + q * 8;

  // fp32 master of x, C-layout: (mt,nt)[j] = row 16mt+4q+j, col ncol[nt]
  f32x4 xr[4][4];
#pragma unroll
  for (int mt = 0; mt < 4; ++mt)
#pragma unroll
    for (int j = 0; j < 4; ++j) {
      int gr = blk * 64 + mt * 16 + q * 4 + j;
#pragma unroll
      for (int nt = 0; nt < 4; ++nt)
        xr[mt][nt][j] = x0[gr * 512 + ncol[nt]];
    }

  // initial bf16 image
#pragma unroll
  for (int mt = 0; mt < 4; ++mt)
#pragma unroll
    for (int j = 0; j < 4; ++j) {
      int m = mt * 16 + q * 4 + j;
#pragma unroll
      for (int nt = 0; nt < 4; ++nt)
        xs[m * XS_STRIDE + ncol[nt]] = f2bf(xr[mt][nt][j]);
    }

  const float sq2b = sqrtf(0.02f);   // sqrt(2*beta)
  const f32x4 vzero = {0.0f, 0.0f, 0.0f, 0.0f};

  for (int t = 0; t < NSTEP; ++t) {
    // key_t = fold_in(key(42), t) = threefry((0,42),(0,t))
    uint32_t kt0 = 0u, kt1 = (uint32_t)t;
    tf_rounds(0u, 42u, 42u ^ 0x1BD11BDAu, kt0, kt1);
    const uint32_t kk2 = kt0 ^ kt1 ^ 0x1BD11BDAu;

    __syncthreads();   // xs writes (init / prev step) visible to all waves

    f32x4 acc[4][4];
#pragma unroll
    for (int mt = 0; mt < 4; ++mt)
#pragma unroll
      for (int nt = 0; nt < 4; ++nt)
        acc[mt][nt] = vzero;

    // ---- K-loop: no barriers; B prefetched one chunk ahead ----
    short8 bf[4], bfn[4];
#pragma unroll
    for (int nt = 0; nt < 4; ++nt)
      bf[nt] = *(const short8*)(bbase[nt]);           // chunk 0

    for (int c = 0; c < 16; ++c) {
      int cn = (c + 1) & 15;
#pragma unroll
      for (int nt = 0; nt < 4; ++nt)
        bfn[nt] = *(const short8*)(bbase[nt] + cn * 16384);
      short8 af[4];
#pragma unroll
      for (int mt = 0; mt < 4; ++mt)
        af[mt] = *(const short8*)&xs[(mt * 16 + l15) * XS_STRIDE + c * 32 + q * 8];
#pragma unroll
      for (int mt = 0; mt < 4; ++mt)
#pragma unroll
        for (int nt = 0; nt < 4; ++nt)
          acc[mt][nt] = __builtin_amdgcn_mfma_f32_16x16x32_bf16(
              af[mt], bf[nt], acc[mt][nt], 0, 0, 0);
#pragma unroll
      for (int nt = 0; nt < 4; ++nt)
        bf[nt] = bfn[nt];
    }

    // ---- noise + update (VALU only, no xs access -> still barrier-free) ----
    const float tf = (float)t;
    float tc[4];
#pragma unroll
    for (int nt = 0; nt < 4; ++nt) tc[nt] = fmaf(tf, csr[nt], br[nt]);

#pragma unroll
    for (int mt = 0; mt < 4; ++mt) {
#pragma unroll
      for (int nt = 0; nt < 4; ++nt) {
        const uint32_t ebase =
            (uint32_t)((blk * 64 + mt * 16 + q * 4) * 512 + ncol[nt]);
#pragma unroll
        for (int j = 0; j < 4; ++j) {
          uint32_t a = 0u, b = ebase + (uint32_t)(j * 512);
          tf_rounds(kt0, kt1, kk2, a, b);
          float n = gauss_from_bits(a ^ b);
          float sc = acc[mt][nt][j] + tc[nt];
          float xv = fmaf(0.01f, sc, xr[mt][nt][j]);  // x + B*score
          xv = fmaf(sq2b, n, xv);                     // + s*noise (ref order)
          xr[mt][nt][j] = xv;
        }
      }
    }

    __syncthreads();   // all waves done reading xs for this step

    // short xs-rewrite phase (fenced by the barrier above + loop-top barrier)
#pragma unroll
    for (int mt = 0; mt < 4; ++mt)
#pragma unroll
      for (int j = 0; j < 4; ++j) {
        int m = mt * 16 + q * 4 + j;
#pragma unroll
        for (int nt = 0; nt < 4; ++nt)
          xs[m * XS_STRIDE + ncol[nt]] = f2bf(xr[mt][nt][j]);
      }
  }

  // final store (fp32)
#pragma unroll
  for (int mt = 0; mt < 4; ++mt)
#pragma unroll
    for (int j = 0; j < 4; ++j) {
      int gr = blk * 64 + mt * 16 + q * 4 + j;
#pragma unroll
      for (int nt = 0; nt < 4; ++nt)
        out[gr * 512 + ncol[nt]] = xr[mt][nt][j];
    }
}

extern "C" void kernel_launch(void* const* d_in, const int* in_sizes, int n_in,
                              void* d_out, int out_size, void* d_ws, size_t ws_size,
                              hipStream_t stream) {
  const float* x0 = (const float*)d_in[0];   // (32768, 512)
  const float* W  = (const float*)d_in[1];   // (1024, 512)
  const float* bv = (const float*)d_in[2];   // (512,)
  float* out = (float*)d_out;

  uint16_t* blob = (uint16_t*)d_ws;                     // 512 KB bf16 W-blob
  float* csum = (float*)((char*)d_ws + 16 * 16384 * 2); // +2 KB

  prep_w_kernel<<<dim3(1024), dim3(256), 0, stream>>>(W, blob);
  prep_csum_kernel<<<dim3(2), dim3(256), 0, stream>>>(W, csum);
  diffuse_kernel<<<dim3(512), dim3(512), 0, stream>>>(x0, blob, csum, bv, out);
}